// Round 3
// baseline (311.011 us; speedup 1.0000x reference)
//
#include <hip/hip_runtime.h>
#include <hip/hip_cooperative_groups.h>
#include <math.h>

#define Bb 256
#define Nn 256
#define Dd 512
#define Cc 1024
#define KC 8          // split-K chunks in logits
#define KD (Dd / KC)  // 64 d per chunk
#define BT 8          // b-tile in logits

namespace cg = cooperative_groups;

__device__ __forceinline__ float waveReduceSum(float v) {
    #pragma unroll
    for (int off = 32; off > 0; off >>= 1)
        v += __shfl_xor(v, off, 64);
    return v;
}
__device__ __forceinline__ float waveReduceMax(float v) {
    #pragma unroll
    for (int off = 32; off > 0; off >>= 1)
        v = fmaxf(v, __shfl_xor(v, off, 64));
    return v;
}

// Single cooperative kernel. grid = 256 blocks (1/CU), 1024 threads.
// Phase A: block b: txt rows [4b,4b+4) norm+transpose -> txt_t; gt-row attn
//          over toks[b] with online softmax -> q[b].
// Phase C: block (kc,b0): split-K logits partials -> part.
// Phase E: block b: sum partials, LSE + NLL -> nll[b].
// Phase F: block 0: mean -> out.
__global__ void __launch_bounds__(1024, 1) k_fused(
    const float* __restrict__ toks, const float* __restrict__ txt,
    const int* __restrict__ pid, const float* __restrict__ log_attn_tau,
    const float* __restrict__ log_tau,
    float* __restrict__ q, float* __restrict__ txt_t,
    float* __restrict__ part, float* __restrict__ nll, float* __restrict__ out)
{
    cg::grid_group grid = cg::this_grid();
    const int bid = blockIdx.x;
    const int tid = threadIdx.x;
    const int wv = tid >> 6;     // 0..15
    const int lane = tid & 63;

    __shared__ float xg[Dd];             // phase A: gt row; phase C: qs overlay
    __shared__ float r8[8];
    __shared__ float tss[16];
    __shared__ float qpart_s[16][Dd];    // 32 KB
    __shared__ float ms[16], Ss[16];
    __shared__ float sgt_s;

    // ================= Phase A: txt prep + attn + q =================
    {
        const int b = bid;
        const int g = pid[b];
        float v = 0.f;
        if (tid < Dd) v = txt[(size_t)g * Dd + tid];

        const int c0 = b * 4;            // 4 text rows per block (C = 4*B)
        const int row = tid >> 8;        // 0..3
        const int col2 = (tid & 255) * 2;
        const float2 tv = *(const float2*)&txt[(size_t)(c0 + row) * Dd + col2];

        float p = waveReduceSum(v * v);
        float ssp = waveReduceSum(tv.x * tv.x + tv.y * tv.y);
        if (lane == 0) { if (wv < 8) r8[wv] = p; tss[wv] = ssp; }
        __syncthreads();

        const float tot = r8[0]+r8[1]+r8[2]+r8[3]+r8[4]+r8[5]+r8[6]+r8[7];
        const float invg = 1.0f / fmaxf(sqrtf(tot), 1e-12f);
        if (tid < Dd) xg[tid] = v * invg;

        {   // own-rows normalize + transposed store
            const float rss = tss[4*row] + tss[4*row+1] + tss[4*row+2] + tss[4*row+3];
            const float invr = 1.0f / fmaxf(sqrtf(rss), 1e-12f);
            txt_t[(size_t)col2 * Cc + c0 + row] = tv.x * invr;
            txt_t[(size_t)(col2 + 1) * Cc + c0 + row] = tv.y * invr;
        }
        __syncthreads();

        float at = expf(log_attn_tau[0]);
        at = fminf(fmaxf(at, 0.01f), 1.0f);
        const float iat = 1.0f / at;

        const float4 xg0 = *(const float4*)&xg[lane * 8];
        const float4 xg1 = *(const float4*)&xg[lane * 8 + 4];

        float m = -INFINITY, S = 0.0f;
        float qa[8] = {0.f, 0.f, 0.f, 0.f, 0.f, 0.f, 0.f, 0.f};

        const float* base = toks + ((size_t)b * Nn + wv * 16) * Dd + (size_t)lane * 8;
        float4 c0v[4], c1v[4];
        #pragma unroll
        for (int k = 0; k < 4; ++k) {
            c0v[k] = *(const float4*)(base + k * Dd);
            c1v[k] = *(const float4*)(base + k * Dd + 4);
        }
        #pragma unroll
        for (int batch = 0; batch < 4; ++batch) {
            float4 n0[4], n1[4];
            if (batch < 3) {   // prefetch next 4 rows
                const float* pn = base + (batch + 1) * 4 * Dd;
                #pragma unroll
                for (int k = 0; k < 4; ++k) {
                    n0[k] = *(const float4*)(pn + k * Dd);
                    n1[k] = *(const float4*)(pn + k * Dd + 4);
                }
            }
            float dt[4], ss[4];
            #pragma unroll
            for (int k = 0; k < 4; ++k) {
                dt[k] = c0v[k].x*xg0.x + c0v[k].y*xg0.y + c0v[k].z*xg0.z + c0v[k].w*xg0.w
                      + c1v[k].x*xg1.x + c1v[k].y*xg1.y + c1v[k].z*xg1.z + c1v[k].w*xg1.w;
                ss[k] = c0v[k].x*c0v[k].x + c0v[k].y*c0v[k].y + c0v[k].z*c0v[k].z + c0v[k].w*c0v[k].w
                      + c1v[k].x*c1v[k].x + c1v[k].y*c1v[k].y + c1v[k].z*c1v[k].z + c1v[k].w*c1v[k].w;
            }
            #pragma unroll
            for (int off = 32; off > 0; off >>= 1) {
                #pragma unroll
                for (int k = 0; k < 4; ++k) {
                    dt[k] += __shfl_xor(dt[k], off, 64);
                    ss[k] += __shfl_xor(ss[k], off, 64);
                }
            }
            #pragma unroll
            for (int k = 0; k < 4; ++k) {
                const float inv = 1.0f / fmaxf(sqrtf(ss[k]), 1e-12f);
                const float s = dt[k] * inv;   // lane-invariant -> wave-uniform branch
                if (s > m) {
                    const float sc = expf((m - s) * iat);   // first row: exp(-inf)=0
                    S = S * sc + 1.0f;
                    qa[0] = qa[0]*sc + inv*c0v[k].x; qa[1] = qa[1]*sc + inv*c0v[k].y;
                    qa[2] = qa[2]*sc + inv*c0v[k].z; qa[3] = qa[3]*sc + inv*c0v[k].w;
                    qa[4] = qa[4]*sc + inv*c1v[k].x; qa[5] = qa[5]*sc + inv*c1v[k].y;
                    qa[6] = qa[6]*sc + inv*c1v[k].z; qa[7] = qa[7]*sc + inv*c1v[k].w;
                    m = s;
                } else {
                    const float e = expf((s - m) * iat);
                    S += e;
                    const float w = e * inv;
                    qa[0] = fmaf(w, c0v[k].x, qa[0]); qa[1] = fmaf(w, c0v[k].y, qa[1]);
                    qa[2] = fmaf(w, c0v[k].z, qa[2]); qa[3] = fmaf(w, c0v[k].w, qa[3]);
                    qa[4] = fmaf(w, c1v[k].x, qa[4]); qa[5] = fmaf(w, c1v[k].y, qa[5]);
                    qa[6] = fmaf(w, c1v[k].z, qa[6]); qa[7] = fmaf(w, c1v[k].w, qa[7]);
                }
            }
            #pragma unroll
            for (int k = 0; k < 4; ++k) { c0v[k] = n0[k]; c1v[k] = n1[k]; }
        }
        #pragma unroll
        for (int j = 0; j < 8; ++j) qpart_s[wv][lane * 8 + j] = qa[j];
        if (lane == 0) { ms[wv] = m; Ss[wv] = S; }
        __syncthreads();
        if (tid < Dd) {
            float M = -INFINITY;
            #pragma unroll
            for (int w = 0; w < 16; ++w) M = fmaxf(M, ms[w]);
            float Stot = 0.f, acc = 0.f;
            #pragma unroll
            for (int w = 0; w < 16; ++w) {
                const float sc = expf((ms[w] - M) * iat);
                Stot = fmaf(Ss[w], sc, Stot);
                acc = fmaf(qpart_s[w][tid], sc, acc);
            }
            q[(size_t)b * Dd + tid] = acc / Stot;
        }
    }

    grid.sync();

    // ================= Phase C: split-K logits =================
    {
        const int kc = bid >> 5;          // 0..7
        const int b0 = (bid & 31) * BT;   // 0..248
        const int d0 = kc * KD;
        float* qs = xg;                   // overlay: BT*KD = 512 floats = 2 KB
        if (tid < BT * KD)
            qs[tid] = q[(size_t)(b0 + (tid >> 6)) * Dd + d0 + (tid & 63)];
        __syncthreads();
        const int c = tid;                // 0..1023, coalesced
        float a[BT];
        #pragma unroll
        for (int j = 0; j < BT; ++j) a[j] = 0.f;
        #pragma unroll 8
        for (int d = 0; d < KD; ++d) {
            const float x = txt_t[(size_t)(d0 + d) * Cc + c];
            #pragma unroll
            for (int j = 0; j < BT; ++j)
                a[j] = fmaf(qs[j * KD + d], x, a[j]);   // lane-uniform LDS broadcast
        }
        float* pb = part + ((size_t)kc * Bb + b0) * Cc + c;
        #pragma unroll
        for (int j = 0; j < BT; ++j) pb[(size_t)j * Cc] = a[j];
    }

    grid.sync();

    // ================= Phase E: LSE + NLL =================
    {
        const int b = bid;
        float l = 0.f;
        #pragma unroll
        for (int kc2 = 0; kc2 < KC; ++kc2)
            l += part[((size_t)kc2 * Bb + b) * Cc + tid];
        float tau = expf(log_tau[0]);
        tau = fminf(fmaxf(tau, 0.01f), 1.0f);
        l *= (1.0f / tau);

        const int g = pid[b];
        if (tid == g) sgt_s = l;
        float m = waveReduceMax(l);
        if (lane == 0) ms[wv] = m;
        __syncthreads();
        float M = -INFINITY;
        #pragma unroll
        for (int w = 0; w < 16; ++w) M = fmaxf(M, ms[w]);
        float e = expf(l - M);
        e = waveReduceSum(e);
        if (lane == 0) Ss[wv] = e;
        __syncthreads();
        if (tid == 0) {
            float S = 0.f;
            #pragma unroll
            for (int w = 0; w < 16; ++w) S += Ss[w];
            nll[b] = M + logf(S) - sgt_s;
        }
    }

    grid.sync();

    // ================= Phase F: mean =================
    if (bid == 0) {
        float v = 0.f;
        if (tid < Bb) v = nll[tid];
        if (tid < Bb) {
            v = waveReduceSum(v);
            if (lane == 0) r8[wv] = v;   // wv 0..3
        }
        __syncthreads();
        if (tid == 0) out[0] = (r8[0] + r8[1] + r8[2] + r8[3]) * (1.0f / (float)Bb);
    }
}

extern "C" void kernel_launch(void* const* d_in, const int* in_sizes, int n_in,
                              void* d_out, int out_size, void* d_ws, size_t ws_size,
                              hipStream_t stream) {
    const float* toks = (const float*)d_in[0];     // [B,N,D] fp32
    const float* txt = (const float*)d_in[1];      // [C,D] fp32
    const float* log_tau = (const float*)d_in[2];
    const float* log_attn_tau = (const float*)d_in[3];
    const int* pid = (const int*)d_in[4];          // [B] int32
    float* out = (float*)d_out;

    float* ws = (float*)d_ws;
    float* txt_t = ws;                             // D*C
    float* q     = txt_t + (size_t)Dd * Cc;        // B*D
    float* part  = q + (size_t)Bb * Dd;            // KC*B*C
    float* nll   = part + (size_t)KC * Bb * Cc;    // B

    void* args[] = {(void*)&toks, (void*)&txt, (void*)&pid, (void*)&log_attn_tau,
                    (void*)&log_tau, (void*)&q, (void*)&txt_t, (void*)&part,
                    (void*)&nll, (void*)&out};
    hipLaunchCooperativeKernel((void*)k_fused, dim3(Bb), dim3(1024), args, 0, stream);
}

// Round 4
// 226.027 us; speedup vs baseline: 1.3760x; 1.3760x over previous
//
#include <hip/hip_runtime.h>
#include <math.h>

#define Bb 256
#define Nn 256
#define Dd 512
#define Cc 1024
#define KC 8          // split-K chunks in logits
#define KD (Dd / KC)  // 64 d per chunk
#define BT 8          // b-tile in logits
#define NS 4          // token-split blocks per b
#define NW 16         // wave-partials per b (NS blocks x 4 waves)

__device__ __forceinline__ float waveReduceSum(float v) {
    #pragma unroll
    for (int off = 32; off > 0; off >>= 1)
        v += __shfl_xor(v, off, 64);
    return v;
}
__device__ __forceinline__ float waveReduceMax(float v) {
    #pragma unroll
    for (int off = 32; off > 0; off >>= 1)
        v = fmaxf(v, __shfl_xor(v, off, 64));
    return v;
}

// Kernel 1: token pass, high occupancy. grid = B*NS = 1024 blocks, 256 threads
// (4 waves). Block (b,s): (a) normalizes txt row c=4b+s -> txt_t (transposed
// store); (b) online softmax over 64 tokens [64s,64s+64), each wave 16 rows,
// emitting per-wave partials pm/pS/pq[ws] (ws = s*4+wv).
__global__ void __launch_bounds__(256, 8) k_attn_part(
    const float* __restrict__ toks, const float* __restrict__ txt,
    const int* __restrict__ pid, const float* __restrict__ log_attn_tau,
    float* __restrict__ txt_t, float* __restrict__ pq,
    float* __restrict__ pm, float* __restrict__ pS,
    float* __restrict__ accf, int* __restrict__ cnt)
{
    const int blk = blockIdx.x;      // = b*NS + s
    const int b = blk >> 2, s = blk & 3;
    const int tid = threadIdx.x;     // 0..255
    const int wv = tid >> 6, lane = tid & 63;
    __shared__ float xg[Dd];
    __shared__ float red_g[4], red_c[4];

    if (blk == 0 && tid == 0) { accf[0] = 0.0f; cnt[0] = 0; }  // finale state

    // ---- txt prep: row c = blk; gt row g = pid[b] ----
    const int c = blk;               // covers 0..1023 exactly once
    const int g = pid[b];
    const float2 gv = *(const float2*)&txt[(size_t)g * Dd + tid * 2];
    const float2 cv = *(const float2*)&txt[(size_t)c * Dd + tid * 2];
    const float pg = waveReduceSum(gv.x * gv.x + gv.y * gv.y);
    const float pc = waveReduceSum(cv.x * cv.x + cv.y * cv.y);
    if (lane == 0) { red_g[wv] = pg; red_c[wv] = pc; }
    __syncthreads();
    const float invg = 1.0f / fmaxf(sqrtf(red_g[0]+red_g[1]+red_g[2]+red_g[3]), 1e-12f);
    const float invc = 1.0f / fmaxf(sqrtf(red_c[0]+red_c[1]+red_c[2]+red_c[3]), 1e-12f);
    xg[tid * 2]     = gv.x * invg;
    xg[tid * 2 + 1] = gv.y * invg;
    txt_t[(size_t)(tid * 2) * Cc + c]     = cv.x * invc;
    txt_t[(size_t)(tid * 2 + 1) * Cc + c] = cv.y * invc;
    __syncthreads();

    float at = expf(log_attn_tau[0]);
    at = fminf(fmaxf(at, 0.01f), 1.0f);
    const float iat = 1.0f / at;

    const float4 xg0 = *(const float4*)&xg[lane * 8];
    const float4 xg1 = *(const float4*)&xg[lane * 8 + 4];

    float m = -INFINITY, S = 0.0f;
    float qa[8] = {0.f, 0.f, 0.f, 0.f, 0.f, 0.f, 0.f, 0.f};

    const float* base = toks + ((size_t)b * Nn + s * 64 + wv * 16) * Dd + (size_t)lane * 8;
    #pragma unroll
    for (int batch = 0; batch < 8; ++batch) {
        float4 c0v[2], c1v[2];
        #pragma unroll
        for (int k = 0; k < 2; ++k) {
            const float* p = base + (size_t)(batch * 2 + k) * Dd;
            c0v[k] = *(const float4*)p;
            c1v[k] = *(const float4*)(p + 4);
        }
        float dt[2], ss[2];
        #pragma unroll
        for (int k = 0; k < 2; ++k) {
            dt[k] = c0v[k].x*xg0.x + c0v[k].y*xg0.y + c0v[k].z*xg0.z + c0v[k].w*xg0.w
                  + c1v[k].x*xg1.x + c1v[k].y*xg1.y + c1v[k].z*xg1.z + c1v[k].w*xg1.w;
            ss[k] = c0v[k].x*c0v[k].x + c0v[k].y*c0v[k].y + c0v[k].z*c0v[k].z + c0v[k].w*c0v[k].w
                  + c1v[k].x*c1v[k].x + c1v[k].y*c1v[k].y + c1v[k].z*c1v[k].z + c1v[k].w*c1v[k].w;
        }
        // 4 interleaved butterflies
        #pragma unroll
        for (int off = 32; off > 0; off >>= 1) {
            #pragma unroll
            for (int k = 0; k < 2; ++k) {
                dt[k] += __shfl_xor(dt[k], off, 64);
                ss[k] += __shfl_xor(ss[k], off, 64);
            }
        }
        #pragma unroll
        for (int k = 0; k < 2; ++k) {
            const float inv = 1.0f / fmaxf(sqrtf(ss[k]), 1e-12f);
            const float sv = dt[k] * inv;   // lane-invariant -> wave-uniform branch
            if (sv > m) {
                const float sc = expf((m - sv) * iat);   // first row: exp(-inf)=0
                S = S * sc + 1.0f;
                qa[0] = qa[0]*sc + inv*c0v[k].x; qa[1] = qa[1]*sc + inv*c0v[k].y;
                qa[2] = qa[2]*sc + inv*c0v[k].z; qa[3] = qa[3]*sc + inv*c0v[k].w;
                qa[4] = qa[4]*sc + inv*c1v[k].x; qa[5] = qa[5]*sc + inv*c1v[k].y;
                qa[6] = qa[6]*sc + inv*c1v[k].z; qa[7] = qa[7]*sc + inv*c1v[k].w;
                m = sv;
            } else {
                const float e = expf((sv - m) * iat);
                S += e;
                const float w = e * inv;
                qa[0] = fmaf(w, c0v[k].x, qa[0]); qa[1] = fmaf(w, c0v[k].y, qa[1]);
                qa[2] = fmaf(w, c0v[k].z, qa[2]); qa[3] = fmaf(w, c0v[k].w, qa[3]);
                qa[4] = fmaf(w, c1v[k].x, qa[4]); qa[5] = fmaf(w, c1v[k].y, qa[5]);
                qa[6] = fmaf(w, c1v[k].z, qa[6]); qa[7] = fmaf(w, c1v[k].w, qa[7]);
            }
        }
    }
    // per-wave partial out (no second block reduction -> tiny LDS, high occ)
    const int ws = s * 4 + wv;       // 0..15
    float* pqw = pq + ((size_t)b * NW + ws) * Dd + lane * 8;
    #pragma unroll
    for (int j = 0; j < 8; ++j) pqw[j] = qa[j];
    if (lane == 0) { pm[b * NW + ws] = m; pS[b * NW + ws] = S; }
}

// Kernel 2: combine partials (in-prologue) + split-K logits.
// grid = (B/BT, KC), 256 threads.
__global__ void k_logits(const float* __restrict__ pq, const float* __restrict__ pm,
                         const float* __restrict__ pS, const float* __restrict__ log_attn_tau,
                         const float* __restrict__ txt_t, float* __restrict__ part)
{
    const int b0 = blockIdx.x * BT;
    const int kc = blockIdx.y;
    const int d0 = kc * KD;
    const int t = threadIdx.x;
    __shared__ float qs[BT][KD];

    float at = expf(log_attn_tau[0]);
    at = fminf(fmaxf(at, 0.01f), 1.0f);
    const float iat = 1.0f / at;

    // combine 16 wave-partials per b into qs (same order as previous rounds)
    for (int slot = t; slot < BT * KD; slot += 256) {
        const int j = slot >> 6, d = slot & 63;
        const int b = b0 + j;
        float M = -INFINITY;
        #pragma unroll
        for (int w = 0; w < NW; ++w) M = fmaxf(M, pm[b * NW + w]);
        float Stot = 0.f, acc = 0.f;
        #pragma unroll
        for (int w = 0; w < NW; ++w) {
            const float sc = expf((pm[b * NW + w] - M) * iat);
            Stot = fmaf(pS[b * NW + w], sc, Stot);
            acc = fmaf(sc, pq[((size_t)b * NW + w) * Dd + d0 + d], acc);
        }
        qs[j][d] = acc / Stot;
    }
    __syncthreads();

    const float4* xt = (const float4*)txt_t;   // [D][C/4]
    float4 a[BT];
    #pragma unroll
    for (int j = 0; j < BT; ++j) a[j] = make_float4(0.f, 0.f, 0.f, 0.f);
    #pragma unroll 2
    for (int d = 0; d < KD; d += 4) {
        const float4 x0 = xt[(size_t)(d0 + d + 0) * (Cc / 4) + t];
        const float4 x1 = xt[(size_t)(d0 + d + 1) * (Cc / 4) + t];
        const float4 x2 = xt[(size_t)(d0 + d + 2) * (Cc / 4) + t];
        const float4 x3 = xt[(size_t)(d0 + d + 3) * (Cc / 4) + t];
        #pragma unroll
        for (int j = 0; j < BT; ++j) {
            const float4 qj = *(const float4*)&qs[j][d];   // lane-uniform LDS broadcast
            a[j].x = fmaf(qj.x,x0.x,a[j].x); a[j].y = fmaf(qj.x,x0.y,a[j].y); a[j].z = fmaf(qj.x,x0.z,a[j].z); a[j].w = fmaf(qj.x,x0.w,a[j].w);
            a[j].x = fmaf(qj.y,x1.x,a[j].x); a[j].y = fmaf(qj.y,x1.y,a[j].y); a[j].z = fmaf(qj.y,x1.z,a[j].z); a[j].w = fmaf(qj.y,x1.w,a[j].w);
            a[j].x = fmaf(qj.z,x2.x,a[j].x); a[j].y = fmaf(qj.z,x2.y,a[j].y); a[j].z = fmaf(qj.z,x2.z,a[j].z); a[j].w = fmaf(qj.z,x2.w,a[j].w);
            a[j].x = fmaf(qj.w,x3.x,a[j].x); a[j].y = fmaf(qj.w,x3.y,a[j].y); a[j].z = fmaf(qj.w,x3.z,a[j].z); a[j].w = fmaf(qj.w,x3.w,a[j].w);
        }
    }
    float* pb = part + ((size_t)kc * Bb + b0) * Cc;
    #pragma unroll
    for (int j = 0; j < BT; ++j) ((float4*)(pb + (size_t)j * Cc))[t] = a[j];
}

// Kernel 3 (fused lse + mean): sum K-partials, scale by 1/tau, LSE + NLL, then
// device-scope atomic mean with last-block finale. grid = B blocks, 256 threads.
__global__ void k_lse_mean(const float* __restrict__ part, const int* __restrict__ pid,
                           const float* __restrict__ log_tau,
                           float* __restrict__ accf, int* __restrict__ cnt,
                           float* __restrict__ out) {
    const int b = blockIdx.x;
    const int t = threadIdx.x;   // 4 c's each
    float4 l = {0,0,0,0};
    #pragma unroll
    for (int kc = 0; kc < KC; ++kc) {
        const float4 p = ((const float4*)(part + ((size_t)kc * Bb + b) * Cc))[t];
        l.x += p.x; l.y += p.y; l.z += p.z; l.w += p.w;
    }
    float tau = expf(log_tau[0]);
    tau = fminf(fmaxf(tau, 0.01f), 1.0f);
    const float itau = 1.0f / tau;
    l.x *= itau; l.y *= itau; l.z *= itau; l.w *= itau;

    const int g = pid[b];
    __shared__ float redm[4], reds[4], sgt;
    if ((g >> 2) == t) {
        const float v[4] = {l.x, l.y, l.z, l.w};
        sgt = v[g & 3];
    }
    float m = fmaxf(fmaxf(l.x, l.y), fmaxf(l.z, l.w));
    m = waveReduceMax(m);
    if ((t & 63) == 0) redm[t >> 6] = m;
    __syncthreads();
    m = fmaxf(fmaxf(redm[0], redm[1]), fmaxf(redm[2], redm[3]));
    float e = expf(l.x - m) + expf(l.y - m) + expf(l.z - m) + expf(l.w - m);
    e = waveReduceSum(e);
    if ((t & 63) == 0) reds[t >> 6] = e;
    __syncthreads();
    if (t == 0) {
        const float S = reds[0] + reds[1] + reds[2] + reds[3];
        const float my = (m + logf(S) - sgt) * (1.0f / (float)Bb);
        atomicAdd(accf, my);
        __threadfence();
        const int c = atomicAdd(cnt, 1);
        if (c == Bb - 1) {
            out[0] = atomicAdd(accf, 0.0f);
        }
    }
}

extern "C" void kernel_launch(void* const* d_in, const int* in_sizes, int n_in,
                              void* d_out, int out_size, void* d_ws, size_t ws_size,
                              hipStream_t stream) {
    const float* toks = (const float*)d_in[0];     // [B,N,D] fp32
    const float* txt = (const float*)d_in[1];      // [C,D] fp32
    const float* log_tau = (const float*)d_in[2];
    const float* log_attn_tau = (const float*)d_in[3];
    const int* pid = (const int*)d_in[4];          // [B] int32
    float* out = (float*)d_out;

    float* ws = (float*)d_ws;
    float* txt_t = ws;                             // D*C
    float* pq    = txt_t + (size_t)Dd * Cc;        // B*NW*D
    float* pm    = pq + (size_t)Bb * NW * Dd;      // B*NW
    float* pS    = pm + (size_t)Bb * NW;           // B*NW
    float* part  = pS + (size_t)Bb * NW;           // KC*B*C
    float* accf  = part + (size_t)KC * Bb * Cc;    // 1
    int*   cnt   = (int*)(accf + 1);               // 1

    k_attn_part<<<Bb * NS, 256, 0, stream>>>(toks, txt, pid, log_attn_tau,
                                             txt_t, pq, pm, pS, accf, cnt);
    k_logits<<<dim3(Bb / BT, KC), 256, 0, stream>>>(pq, pm, pS, log_attn_tau, txt_t, part);
    k_lse_mean<<<Bb, 256, 0, stream>>>(part, pid, log_tau, accf, cnt, out);
}

// Round 5
// 218.276 us; speedup vs baseline: 1.4248x; 1.0355x over previous
//
#include <hip/hip_runtime.h>
#include <math.h>

#define Bb 256
#define Nn 256
#define Dd 512
#define Cc 1024
#define KC 8          // split-K chunks in logits
#define KD (Dd / KC)  // 64 d per chunk

__device__ __forceinline__ float waveReduceSum(float v) {
    #pragma unroll
    for (int off = 32; off > 0; off >>= 1)
        v += __shfl_xor(v, off, 64);
    return v;
}
__device__ __forceinline__ float waveReduceMax(float v) {
    #pragma unroll
    for (int off = 32; off > 0; off >>= 1)
        v = fmaxf(v, __shfl_xor(v, off, 64));
    return v;
}

// A: normalize text rows. grid = Cc blocks, 64 threads (1 wave).
__global__ void k_txtnorm(const float* __restrict__ txt, float* __restrict__ txt_n) {
    const int c = blockIdx.x;
    const int lane = threadIdx.x;
    const float* row = txt + (size_t)c * Dd + lane * 8;
    float4 a = *(const float4*)row;
    float4 b = *(const float4*)(row + 4);
    float ss = a.x*a.x + a.y*a.y + a.z*a.z + a.w*a.w
             + b.x*b.x + b.y*b.y + b.z*b.z + b.w*b.w;
    ss = waveReduceSum(ss);
    const float inv = 1.0f / fmaxf(sqrtf(ss), 1e-12f);
    float* out = txt_n + (size_t)c * Dd + lane * 8;
    a.x *= inv; a.y *= inv; a.z *= inv; a.w *= inv;
    b.x *= inv; b.y *= inv; b.z *= inv; b.w *= inv;
    *(float4*)out = a;
    *(float4*)(out + 4) = b;
}

// A2: transpose txt_n [C,D] -> txt_t [D,C]. grid = (C/32, D/32), 256 threads.
__global__ void k_transpose(const float* __restrict__ txt_n, float* __restrict__ txt_t) {
    __shared__ float tile[32][33];
    const int c0 = blockIdx.x * 32;
    const int d0 = blockIdx.y * 32;
    const int tx = threadIdx.x & 31;
    const int ty = threadIdx.x >> 5;
    #pragma unroll
    for (int r = ty; r < 32; r += 8)
        tile[r][tx] = txt_n[(size_t)(c0 + r) * Dd + d0 + tx];
    __syncthreads();
    #pragma unroll
    for (int r = ty; r < 32; r += 8)
        txt_t[(size_t)(d0 + r) * Cc + c0 + tx] = tile[tx][r];
}

// B (fused simgt+softmax+qpart): ONE pass over tokens with online softmax.
// grid = B blocks, 1024 threads (16 waves, 16 rows each).
// q[b][d] = sum_n softmax_n(sims_gt/at) * invn_n * tok[b][n][d]
__global__ void __launch_bounds__(1024) k_attn_q(const float* __restrict__ toks,
                                                 const float* __restrict__ txt_n,
                                                 const int* __restrict__ pid,
                                                 const float* __restrict__ log_attn_tau,
                                                 float* __restrict__ q) {
    const int b = blockIdx.x;
    const int tid = threadIdx.x;
    const int wv = tid >> 6;     // 0..15
    const int lane = tid & 63;
    __shared__ float xg[Dd];
    __shared__ float qpart_s[16][Dd];   // 32 KB
    __shared__ float ms[16], Ss[16];
    const int g = pid[b];
    if (tid < Dd) xg[tid] = txt_n[(size_t)g * Dd + tid];
    __syncthreads();
    float at = expf(log_attn_tau[0]);
    at = fminf(fmaxf(at, 0.01f), 1.0f);
    const float iat = 1.0f / at;

    const float4 xg0 = *(const float4*)&xg[lane * 8];
    const float4 xg1 = *(const float4*)&xg[lane * 8 + 4];

    float m = -INFINITY, S = 0.0f;
    float qa[8] = {0.f, 0.f, 0.f, 0.f, 0.f, 0.f, 0.f, 0.f};

    const float* base = toks + ((size_t)b * Nn + wv * 16) * Dd + lane * 8;
    float4 t0 = *(const float4*)base;
    float4 t1 = *(const float4*)(base + 4);
    #pragma unroll 4
    for (int r = 0; r < 16; ++r) {
        float4 n0, n1;
        if (r < 15) {   // prefetch next row
            const float* p = base + (size_t)(r + 1) * Dd;
            n0 = *(const float4*)p;
            n1 = *(const float4*)(p + 4);
        }
        float dot = t0.x*xg0.x + t0.y*xg0.y + t0.z*xg0.z + t0.w*xg0.w
                  + t1.x*xg1.x + t1.y*xg1.y + t1.z*xg1.z + t1.w*xg1.w;
        float ss  = t0.x*t0.x + t0.y*t0.y + t0.z*t0.z + t0.w*t0.w
                  + t1.x*t1.x + t1.y*t1.y + t1.z*t1.z + t1.w*t1.w;
        dot = waveReduceSum(dot);
        ss = waveReduceSum(ss);
        const float inv = 1.0f / fmaxf(sqrtf(ss), 1e-12f);
        const float s = dot * inv;     // lane-invariant -> wave-uniform branch
        if (s > m) {
            const float sc = expf((m - s) * iat);   // first iter: exp(-inf)=0
            S = S * sc + 1.0f;
            qa[0] = qa[0]*sc + inv*t0.x; qa[1] = qa[1]*sc + inv*t0.y;
            qa[2] = qa[2]*sc + inv*t0.z; qa[3] = qa[3]*sc + inv*t0.w;
            qa[4] = qa[4]*sc + inv*t1.x; qa[5] = qa[5]*sc + inv*t1.y;
            qa[6] = qa[6]*sc + inv*t1.z; qa[7] = qa[7]*sc + inv*t1.w;
            m = s;
        } else {
            const float e = expf((s - m) * iat);
            S += e;
            const float w = e * inv;
            qa[0] = fmaf(w, t0.x, qa[0]); qa[1] = fmaf(w, t0.y, qa[1]);
            qa[2] = fmaf(w, t0.z, qa[2]); qa[3] = fmaf(w, t0.w, qa[3]);
            qa[4] = fmaf(w, t1.x, qa[4]); qa[5] = fmaf(w, t1.y, qa[5]);
            qa[6] = fmaf(w, t1.z, qa[6]); qa[7] = fmaf(w, t1.w, qa[7]);
        }
        t0 = n0; t1 = n1;
    }
    #pragma unroll
    for (int j = 0; j < 8; ++j) qpart_s[wv][lane * 8 + j] = qa[j];
    if (lane == 0) { ms[wv] = m; Ss[wv] = S; }
    __syncthreads();
    if (tid < Dd) {
        float M = -INFINITY;
        #pragma unroll
        for (int w = 0; w < 16; ++w) M = fmaxf(M, ms[w]);
        float Stot = 0.f, acc = 0.f;
        #pragma unroll
        for (int w = 0; w < 16; ++w) {
            const float sc = expf((ms[w] - M) * iat);
            Stot = fmaf(Ss[w], sc, Stot);
            acc = fmaf(qpart_s[w][tid], sc, acc);
        }
        q[(size_t)b * Dd + tid] = acc / Stot;
    }
}

// E: split-K logits partials. grid = (B/4, KC), 256 threads.
// part[kc][b][c] = sum_{d in chunk} q[b][d] * txt_t[d][c]
__global__ void k_logits(const float* __restrict__ q, const float* __restrict__ txt_t,
                         float* __restrict__ part) {
    const int b0 = blockIdx.x * 4;
    const int kc = blockIdx.y;
    const int d0 = kc * KD;
    const int t = threadIdx.x;     // covers 4 c's each (float4), 1024 c total
    __shared__ float qs[4][KD];
    {
        const int j = t >> 6, d = t & 63;
        qs[j][d] = q[(size_t)(b0 + j) * Dd + d0 + d];
    }
    __syncthreads();
    const float4* xt = (const float4*)txt_t;   // [D][C/4]
    float4 a0 = {0,0,0,0}, a1 = {0,0,0,0}, a2 = {0,0,0,0}, a3 = {0,0,0,0};
    #pragma unroll 4
    for (int d = 0; d < KD; d += 4) {
        const float4 q0 = *(const float4*)&qs[0][d];
        const float4 q1 = *(const float4*)&qs[1][d];
        const float4 q2 = *(const float4*)&qs[2][d];
        const float4 q3 = *(const float4*)&qs[3][d];
        const float4 x0 = xt[(size_t)(d0 + d + 0) * (Cc / 4) + t];
        const float4 x1 = xt[(size_t)(d0 + d + 1) * (Cc / 4) + t];
        const float4 x2 = xt[(size_t)(d0 + d + 2) * (Cc / 4) + t];
        const float4 x3 = xt[(size_t)(d0 + d + 3) * (Cc / 4) + t];
        a0.x = fmaf(q0.x,x0.x,a0.x); a0.y = fmaf(q0.x,x0.y,a0.y); a0.z = fmaf(q0.x,x0.z,a0.z); a0.w = fmaf(q0.x,x0.w,a0.w);
        a0.x = fmaf(q0.y,x1.x,a0.x); a0.y = fmaf(q0.y,x1.y,a0.y); a0.z = fmaf(q0.y,x1.z,a0.z); a0.w = fmaf(q0.y,x1.w,a0.w);
        a0.x = fmaf(q0.z,x2.x,a0.x); a0.y = fmaf(q0.z,x2.y,a0.y); a0.z = fmaf(q0.z,x2.z,a0.z); a0.w = fmaf(q0.z,x2.w,a0.w);
        a0.x = fmaf(q0.w,x3.x,a0.x); a0.y = fmaf(q0.w,x3.y,a0.y); a0.z = fmaf(q0.w,x3.z,a0.z); a0.w = fmaf(q0.w,x3.w,a0.w);
        a1.x = fmaf(q1.x,x0.x,a1.x); a1.y = fmaf(q1.x,x0.y,a1.y); a1.z = fmaf(q1.x,x0.z,a1.z); a1.w = fmaf(q1.x,x0.w,a1.w);
        a1.x = fmaf(q1.y,x1.x,a1.x); a1.y = fmaf(q1.y,x1.y,a1.y); a1.z = fmaf(q1.y,x1.z,a1.z); a1.w = fmaf(q1.y,x1.w,a1.w);
        a1.x = fmaf(q1.z,x2.x,a1.x); a1.y = fmaf(q1.z,x2.y,a1.y); a1.z = fmaf(q1.z,x2.z,a1.z); a1.w = fmaf(q1.z,x2.w,a1.w);
        a1.x = fmaf(q1.w,x3.x,a1.x); a1.y = fmaf(q1.w,x3.y,a1.y); a1.z = fmaf(q1.w,x3.z,a1.z); a1.w = fmaf(q1.w,x3.w,a1.w);
        a2.x = fmaf(q2.x,x0.x,a2.x); a2.y = fmaf(q2.x,x0.y,a2.y); a2.z = fmaf(q2.x,x0.z,a2.z); a2.w = fmaf(q2.x,x0.w,a2.w);
        a2.x = fmaf(q2.y,x1.x,a2.x); a2.y = fmaf(q2.y,x1.y,a2.y); a2.z = fmaf(q2.y,x1.z,a2.z); a2.w = fmaf(q2.y,x1.w,a2.w);
        a2.x = fmaf(q2.z,x2.x,a2.x); a2.y = fmaf(q2.z,x2.y,a2.y); a2.z = fmaf(q2.z,x2.z,a2.z); a2.w = fmaf(q2.z,x2.w,a2.w);
        a2.x = fmaf(q2.w,x3.x,a2.x); a2.y = fmaf(q2.w,x3.y,a2.y); a2.z = fmaf(q2.w,x3.z,a2.z); a2.w = fmaf(q2.w,x3.w,a2.w);
        a3.x = fmaf(q3.x,x0.x,a3.x); a3.y = fmaf(q3.x,x0.y,a3.y); a3.z = fmaf(q3.x,x0.z,a3.z); a3.w = fmaf(q3.x,x0.w,a3.w);
        a3.x = fmaf(q3.y,x1.x,a3.x); a3.y = fmaf(q3.y,x1.y,a3.y); a3.z = fmaf(q3.y,x1.z,a3.z); a3.w = fmaf(q3.y,x1.w,a3.w);
        a3.x = fmaf(q3.z,x2.x,a3.x); a3.y = fmaf(q3.z,x2.y,a3.y); a3.z = fmaf(q3.z,x2.z,a3.z); a3.w = fmaf(q3.z,x2.w,a3.w);
        a3.x = fmaf(q3.w,x3.x,a3.x); a3.y = fmaf(q3.w,x3.y,a3.y); a3.z = fmaf(q3.w,x3.z,a3.z); a3.w = fmaf(q3.w,x3.w,a3.w);
    }
    float* pb = part + ((size_t)kc * Bb + b0) * Cc;
    ((float4*)(pb + 0 * Cc))[t] = a0;
    ((float4*)(pb + 1 * Cc))[t] = a1;
    ((float4*)(pb + 2 * Cc))[t] = a2;
    ((float4*)(pb + 3 * Cc))[t] = a3;
}

// E2: sum K-partials, scale by 1/tau, LSE + NLL. grid = B blocks, 256 threads.
__global__ void k_lse(const float* __restrict__ part, const int* __restrict__ pid,
                      const float* __restrict__ log_tau, float* __restrict__ nll) {
    const int b = blockIdx.x;
    const int t = threadIdx.x;   // 4 c's each
    float4 l = {0,0,0,0};
    #pragma unroll
    for (int kc = 0; kc < KC; ++kc) {
        const float4 p = ((const float4*)(part + ((size_t)kc * Bb + b) * Cc))[t];
        l.x += p.x; l.y += p.y; l.z += p.z; l.w += p.w;
    }
    float tau = expf(log_tau[0]);
    tau = fminf(fmaxf(tau, 0.01f), 1.0f);
    const float itau = 1.0f / tau;
    l.x *= itau; l.y *= itau; l.z *= itau; l.w *= itau;

    const int g = pid[b];
    __shared__ float redm[4], reds[4], sgt;
    if ((g >> 2) == t) {
        const float v[4] = {l.x, l.y, l.z, l.w};
        sgt = v[g & 3];
    }
    float m = fmaxf(fmaxf(l.x, l.y), fmaxf(l.z, l.w));
    m = waveReduceMax(m);
    if ((t & 63) == 0) redm[t >> 6] = m;
    __syncthreads();
    m = fmaxf(fmaxf(redm[0], redm[1]), fmaxf(redm[2], redm[3]));
    float e = expf(l.x - m) + expf(l.y - m) + expf(l.z - m) + expf(l.w - m);
    e = waveReduceSum(e);
    if ((t & 63) == 0) reds[t >> 6] = e;
    __syncthreads();
    if (t == 0) {
        const float S = reds[0] + reds[1] + reds[2] + reds[3];
        nll[b] = m + logf(S) - sgt;
    }
}

// F: mean over B. 1 block, 256 threads.
__global__ void k_mean(const float* __restrict__ nll, float* __restrict__ out) {
    float v = nll[threadIdx.x];
    __shared__ float red[4];
    v = waveReduceSum(v);
    if ((threadIdx.x & 63) == 0) red[threadIdx.x >> 6] = v;
    __syncthreads();
    if (threadIdx.x == 0) out[0] = (red[0] + red[1] + red[2] + red[3]) * (1.0f / (float)Bb);
}

extern "C" void kernel_launch(void* const* d_in, const int* in_sizes, int n_in,
                              void* d_out, int out_size, void* d_ws, size_t ws_size,
                              hipStream_t stream) {
    const float* toks = (const float*)d_in[0];     // [B,N,D] fp32
    const float* txt = (const float*)d_in[1];      // [C,D] fp32
    const float* log_tau = (const float*)d_in[2];
    const float* log_attn_tau = (const float*)d_in[3];
    const int* pid = (const int*)d_in[4];          // [B] int32
    float* out = (float*)d_out;

    float* ws = (float*)d_ws;
    float* txt_n = ws;                             // C*D
    float* txt_t = txt_n + (size_t)Cc * Dd;        // D*C
    float* q     = txt_t + (size_t)Dd * Cc;        // B*D
    float* part  = q + (size_t)Bb * Dd;            // KC*B*C
    float* nll   = part + (size_t)KC * Bb * Cc;    // B

    k_txtnorm<<<Cc, 64, 0, stream>>>(txt, txt_n);
    k_transpose<<<dim3(Cc / 32, Dd / 32), 256, 0, stream>>>(txt_n, txt_t);
    k_attn_q<<<Bb, 1024, 0, stream>>>(toks, txt_n, pid, log_attn_tau, q);
    k_logits<<<dim3(Bb / 4, KC), 256, 0, stream>>>(q, txt_t, part);
    k_lse<<<Bb, 256, 0, stream>>>(part, pid, log_tau, nll);
    k_mean<<<1, 256, 0, stream>>>(nll, out);
}